// Round 6
// baseline (620.885 us; speedup 1.0000x reference)
//
#include <hip/hip_runtime.h>
#include <hip/hip_bf16.h>
#include <stdint.h>

#define B_SZ   128
#define D_SZ   3072
#define N_SZ   20000
#define NPAD   20480   // 640 n-steps of 32; 313 score n-tiles of 64 (20032)
#define BN     (B_SZ * NPAD)     // 2621440 elems
#define BD     (B_SZ * D_SZ)     // 393216 elems
#define KC_S   4                 // scores K-chunks (768 each, 24 steps)
#define KC_D   40                // drift K-chunks (512 each, 16 steps)
#define NT_S   313               // score n-tiles
#define KS_N   96                // k-steps of 32 over D

typedef __attribute__((ext_vector_type(8))) short          short8;
typedef __attribute__((ext_vector_type(4))) float          f32x4;

__device__ __forceinline__ unsigned short f2bf(float f) {
    unsigned u = __float_as_uint(f);
    u += 0x7FFFu + ((u >> 16) & 1u);   // round-to-nearest-even
    return (unsigned short)(u >> 16);
}
__device__ __forceinline__ float bf2f(unsigned short h) {
    return __uint_as_float(((unsigned)h) << 16);
}
// order-preserving float<->uint key for atomicMax over signed floats
__device__ __forceinline__ unsigned fkey_enc(float f) {
    unsigned b = __float_as_uint(f);
    return (b & 0x80000000u) ? ~b : (b | 0x80000000u);
}
__device__ __forceinline__ float fkey_dec(unsigned u) {
    return __uint_as_float((u & 0x80000000u) ? (u ^ 0x80000000u) : ~u);
}

__device__ __forceinline__ void gl_lds16(const void* g, void* l) {
    __builtin_amdgcn_global_load_lds(
        (const __attribute__((address_space(1))) void*)g,
        (__attribute__((address_space(3))) void*)l, 16, 0, 0);
}

// bank swizzle inside a 64B tile row: chunk q of row r sits at slot swz(r,q).
// Involution; applied at PREP-store time (tiles are stored pre-swizzled) and
// again at ds_read time. gl_lds staging is then fully linear (tid*16).
__device__ __forceinline__ int swz(int r, int q) { return q ^ ((r >> 1) & 3); }

// ---------------- zero G2 + Mkey + L (20736 floats, contiguous) ------------
__global__ __launch_bounds__(256) void zero_small(float* __restrict__ p)
{
    p[blockIdx.x * 256 + threadIdx.x] = 0.f;   // grid 81: 81*256 = 20736
}

// ---------------- prep_x: x -> X_t tiles [ks][hi 128x32][lo 128x32] -------
__global__ __launch_bounds__(256) void prep_x(const float* __restrict__ x,
                                              unsigned short* __restrict__ X_t)
{
    int i = blockIdx.x * 256 + threadIdx.x;     // exactly BD
    int b = i / D_SZ;
    int d = i - b * D_SZ;
    int ks = d >> 5, c = d & 31;
    float v = x[i];
    unsigned short h = f2bf(v);
    unsigned short l = f2bf(v - bf2f(h));
    size_t p = (size_t)ks * 8192 + b * 32 + swz(b, c >> 3) * 8 + (c & 7);
    X_t[p]        = h;
    X_t[p + 4096] = l;
}

// ---------------- prep_gt: gt -> GS (scores tiles), GD (drift tiles), G2 ---
// grid = 320 nblk * 6 dgrp = 1920. Reads gt in 128B/thread contiguous
// chunks (512B per 4 threads). Emits:
//   GS[(nt*96+ks)*4096]: [hi 64x32][lo 64x32], pre-swizzled  (nt<313)
//   GD[(dt*640+ns)*4096]: [128 d][32 n] hi, pre-swizzled (transpose via LDS)
//   G2[n] += sum_d gt^2
// Pad rows (n>=20000) produce exact-zero tiles.
__global__ __launch_bounds__(256) void prep_gt(
        const float* __restrict__ gt,
        unsigned short* __restrict__ GS,
        unsigned short* __restrict__ GD,
        float* __restrict__ G2)
{
    __shared__ unsigned short Lh[64][136];   // 64 x 128 hi + pad (16B-aligned rows)
    const int tid  = threadIdx.x;
    const int nblk = blockIdx.x / 6;    // 0..319
    const int dgrp = blockIdx.x % 6;    // 0..5
    const int r  = tid >> 2, c4 = tid & 3;
    const int n  = nblk * 64 + r;
    const bool nv = (n < N_SZ);
    const int ts = tid >> 7, dr = tid & 127;   // transpose-phase mapping
    float g2 = 0.f;

    for (int cc = 0; cc < 4; cc++) {
        const int dc = dgrp * 4 + cc;      // d-chunk 0..23 (= drift d-tile)
        const int d0 = dc * 128;
        float v[32];
        if (nv) {
            const float* gp = gt + (size_t)n * D_SZ + d0 + c4 * 32;
            #pragma unroll
            for (int i = 0; i < 8; i++) {
                f32x4 xv = *(const f32x4*)(gp + i * 4);
                v[4*i+0]=xv[0]; v[4*i+1]=xv[1]; v[4*i+2]=xv[2]; v[4*i+3]=xv[3];
            }
        } else {
            #pragma unroll
            for (int j = 0; j < 32; j++) v[j] = 0.f;
        }
        __attribute__((aligned(16))) unsigned short h[32], l[32];
        #pragma unroll
        for (int j = 0; j < 32; j++) {
            h[j] = f2bf(v[j]);
            l[j] = f2bf(v[j] - bf2f(h[j]));
            g2 += v[j] * v[j];
        }
        // GS: this thread's 32 elems are exactly row r, ks = dc*4 + c4
        if (nblk < NT_S) {
            size_t base = (size_t)(nblk * KS_N + dc * 4 + c4) * 4096 + r * 32;
            #pragma unroll
            for (int q = 0; q < 4; q++) {
                *(short8*)(GS + base +        swz(r, q) * 8) = *(short8*)&h[q*8];
                *(short8*)(GS + base + 2048 + swz(r, q) * 8) = *(short8*)&l[q*8];
            }
        }
        // LDS stage for transpose
        #pragma unroll
        for (int q = 0; q < 4; q++)
            *(short8*)&Lh[r][c4 * 32 + q * 8] = *(short8*)&h[q*8];
        __syncthreads();
        // GD: tile (dc, ns = nblk*2+ts), row dr, 32 n-cols
        {
            __attribute__((aligned(16))) unsigned short tv[32];
            #pragma unroll
            for (int j = 0; j < 32; j++) tv[j] = Lh[ts * 32 + j][dr];
            size_t base = (size_t)(dc * 640 + nblk * 2 + ts) * 4096 + dr * 32;
            #pragma unroll
            for (int q = 0; q < 4; q++)
                *(short8*)(GD + base + swz(dr, q) * 8) = *(short8*)&tv[q*8];
        }
        __syncthreads();
    }
    g2 += __shfl_xor(g2, 1);
    g2 += __shfl_xor(g2, 2);
    if (c4 == 0 && nv) atomicAdd(&G2[n], g2);
}

// ---------------- scores: XG_part[kc][b][n] = partial x.g -----------------
// grid = 313 nt * 4 kc = 1252. Tile M=128 x N=64, 24 steps of K=32.
// All staging via gl_lds from PRE-TILED GS/X_t: source = base + tid*16,
// fully contiguous -> DRAM-sequential. 2-buffer, one barrier per step.
// split-precision: acc = xhi*ghi + xhi*glo + xlo*ghi
__global__ __launch_bounds__(256) void scores_kernel(
        const unsigned short* __restrict__ GS,
        const unsigned short* __restrict__ X_t,
        float* __restrict__ XG_part)
{
    __shared__ __align__(16) unsigned short Xh[2][4096];
    __shared__ __align__(16) unsigned short Xl[2][4096];
    __shared__ __align__(16) unsigned short Gh[2][2048];
    __shared__ __align__(16) unsigned short Gl[2][2048];   // 48 KB

    const int tid   = threadIdx.x;
    const int kc    = blockIdx.x & 3;
    const int nt    = blockIdx.x >> 2;
    const int nbase = nt * 64;

    const int lane = tid & 63;
    const int wave = tid >> 6;
    const int mh = wave & 1;
    const int nh = wave >> 1;
    const int lm = lane & 15;
    const int qd = lane >> 4;

    f32x4 acc[4][2];
    #pragma unroll
    for (int i = 0; i < 4; i++)
        #pragma unroll
        for (int j = 0; j < 2; j++)
            acc[i][j] = (f32x4){0.f, 0.f, 0.f, 0.f};

#define STAGE_S(ks_, bb) do {                                               \
        size_t xb = (size_t)(ks_) * 8192;                                   \
        size_t gb = (size_t)(nt * KS_N + (ks_)) * 4096;                     \
        gl_lds16(X_t + xb +        tid * 8, (char*)Xh[bb] + tid * 16);      \
        gl_lds16(X_t + xb + 2048 + tid * 8, (char*)Xh[bb] + 4096 + tid * 16);\
        gl_lds16(X_t + xb + 4096 + tid * 8, (char*)Xl[bb] + tid * 16);      \
        gl_lds16(X_t + xb + 6144 + tid * 8, (char*)Xl[bb] + 4096 + tid * 16);\
        gl_lds16(GS  + gb +        tid * 8, (char*)Gh[bb] + tid * 16);      \
        gl_lds16(GS  + gb + 2048 + tid * 8, (char*)Gl[bb] + tid * 16);      \
    } while (0)

    STAGE_S(kc * 24, 0);
    __syncthreads();

    for (int t = 0; t < 24; t++) {
        const int buf = t & 1;
        if (t < 23) STAGE_S(kc * 24 + t + 1, buf ^ 1);

        short8 bhi[2], blo[2];
        #pragma unroll
        for (int ni = 0; ni < 2; ni++) {
            int r = nh * 32 + ni * 16 + lm;
            int sl = r * 32 + swz(r, qd) * 8;
            bhi[ni] = *(short8*)&Gh[buf][sl];
            blo[ni] = *(short8*)&Gl[buf][sl];
        }
        #pragma unroll
        for (int mi = 0; mi < 4; mi++) {
            int r = mh * 64 + mi * 16 + lm;
            int sl = r * 32 + swz(r, qd) * 8;
            short8 ahi = *(short8*)&Xh[buf][sl];
            short8 alo = *(short8*)&Xl[buf][sl];
            #pragma unroll
            for (int ni = 0; ni < 2; ni++) {
                acc[mi][ni] = __builtin_amdgcn_mfma_f32_16x16x32_bf16(ahi, bhi[ni], acc[mi][ni], 0, 0, 0);
                acc[mi][ni] = __builtin_amdgcn_mfma_f32_16x16x32_bf16(ahi, blo[ni], acc[mi][ni], 0, 0, 0);
                acc[mi][ni] = __builtin_amdgcn_mfma_f32_16x16x32_bf16(alo, bhi[ni], acc[mi][ni], 0, 0, 0);
            }
        }
        __syncthreads();   // drains the prefetch too (BW-bound: stall << step)
    }
#undef STAGE_S

    float* XGp = XG_part + (size_t)kc * BN;
    #pragma unroll
    for (int mi = 0; mi < 4; mi++) {
        #pragma unroll
        for (int ni = 0; ni < 2; ni++) {
            int ncol = nh * 32 + ni * 16 + lm;
            int ng = nbase + ncol;
            if (ng < N_SZ) {
                #pragma unroll
                for (int i = 0; i < 4; i++) {
                    int m = mh * 64 + mi * 16 + qd * 4 + i;
                    XGp[(size_t)m * NPAD + ng] = acc[mi][ni][i];
                }
            }
        }
    }
}

// ---------------- sum4max: XG = sum_kc XG_part[kc]; fused row-max ---------
__global__ __launch_bounds__(256) void sum4max(
        const float* __restrict__ XG_part, const float* __restrict__ G2,
        const float* __restrict__ tarr, float* __restrict__ XG,
        unsigned* __restrict__ Mkey)
{
    const int tid = threadIdx.x;
    const int b = blockIdx.x / 20;
    const int i = (blockIdx.x * 256 + tid) * 4;
    __shared__ float wred[4];

    f32x4 s = (f32x4){0.f, 0.f, 0.f, 0.f};
    #pragma unroll
    for (int kc = 0; kc < KC_S; kc++)
        s += *(const f32x4*)(XG_part + (size_t)kc * BN + i);
    *(f32x4*)(XG + i) = s;

    float tt  = tarr[b] / 999.0f;
    float sig = 1.0f - tt;
    float inv = 1.0f / (sig * sig);
    float c1 = tt * inv, c2 = 0.5f * tt * tt * inv;
    int n = i - b * NPAD;

    float mx = -3.402823466e+38f;
    #pragma unroll
    for (int j = 0; j < 4; j++)
        if (n + j < N_SZ) mx = fmaxf(mx, c1 * s[j] - c2 * G2[n + j]);
    #pragma unroll
    for (int o = 32; o > 0; o >>= 1) mx = fmaxf(mx, __shfl_xor(mx, o));
    if ((tid & 63) == 0) wred[tid >> 6] = mx;
    __syncthreads();
    if (tid == 0) {
        mx = fmaxf(fmaxf(wred[0], wred[1]), fmaxf(wred[2], wred[3]));
        atomicMax(&Mkey[b], fkey_enc(mx));
    }
}

// ---------------- expk: P_t tiles = bf16(exp(s - m)), L[b] += sum ---------
// P written PRE-TILED [ns][128 b][32 n] pre-swizzled for drift's gl_lds.
__global__ __launch_bounds__(256) void expk(
        const float* __restrict__ XG, const float* __restrict__ G2,
        const float* __restrict__ tarr, const unsigned* __restrict__ Mkey,
        unsigned short* __restrict__ P_t, float* __restrict__ L)
{
    const int b  = blockIdx.x >> 3;
    const int ch = blockIdx.x & 7;
    const int tid = threadIdx.x;
    float tt  = tarr[b] / 999.0f;
    float sig = 1.0f - tt;
    float inv = 1.0f / (sig * sig);
    float c1 = tt * inv, c2 = 0.5f * tt * tt * inv;
    float m = fkey_dec(Mkey[b]);
    const float* xg = XG + (size_t)b * NPAD;
    __shared__ float wred[4];

    float sum = 0.f;
    int n0 = ch * 2560;
    for (int n = n0 + tid; n < n0 + 2560; n += 256) {
        float p = 0.f;
        if (n < N_SZ) { p = expf(c1 * xg[n] - c2 * G2[n] - m); sum += p; }
        int c = n & 31;
        P_t[(size_t)(n >> 5) * 4096 + b * 32 + swz(b, c >> 3) * 8 + (c & 7)] = f2bf(p);
    }
    #pragma unroll
    for (int o = 32; o > 0; o >>= 1) sum += __shfl_xor(sum, o);
    if ((tid & 63) == 0) wred[tid >> 6] = sum;
    __syncthreads();
    if (tid == 0) atomicAdd(&L[b], wred[0] + wred[1] + wred[2] + wred[3]);
}

// ---------------- drift: Dacc_part[kc][b][d] = partial P.G^T --------------
// grid = 24 dt * 40 kc = 960; 16 steps of 32 n. Both operands PRE-TILED
// (P_t from expk, GD from prep_gt): gl_lds sources fully contiguous.
__global__ __launch_bounds__(256) void drift_kernel(
        const unsigned short* __restrict__ GD,
        const unsigned short* __restrict__ P_t,
        float* __restrict__ Dacc_part)
{
    __shared__ __align__(16) unsigned short Pt[2][4096];
    __shared__ __align__(16) unsigned short Gt[2][4096];   // 32 KB

    const int tid = threadIdx.x;
    const int dt = blockIdx.x % 24;
    const int kc = blockIdx.x / 24;     // 0..39
    const int dbase = dt * 128;

    const int lane = tid & 63;
    const int wave = tid >> 6;
    const int mh = wave & 1;
    const int dh = wave >> 1;
    const int lm = lane & 15;
    const int qd = lane >> 4;

    f32x4 acc[4][4];
    #pragma unroll
    for (int i = 0; i < 4; i++)
        #pragma unroll
        for (int j = 0; j < 4; j++)
            acc[i][j] = (f32x4){0.f, 0.f, 0.f, 0.f};

#define STAGE_D(ns_, bb) do {                                               \
        size_t pb = (size_t)(ns_) * 4096;                                   \
        size_t gb = (size_t)(dt * 640 + (ns_)) * 4096;                      \
        gl_lds16(P_t + pb +        tid * 8, (char*)Pt[bb] + tid * 16);      \
        gl_lds16(P_t + pb + 2048 + tid * 8, (char*)Pt[bb] + 4096 + tid * 16);\
        gl_lds16(GD  + gb +        tid * 8, (char*)Gt[bb] + tid * 16);      \
        gl_lds16(GD  + gb + 2048 + tid * 8, (char*)Gt[bb] + 4096 + tid * 16);\
    } while (0)

    STAGE_D(kc * 16, 0);
    __syncthreads();

    for (int s = 0; s < 16; s++) {
        const int buf = s & 1;
        if (s < 15) STAGE_D(kc * 16 + s + 1, buf ^ 1);

        short8 af[4], bf8[4];
        #pragma unroll
        for (int mi = 0; mi < 4; mi++) {
            int r = mh * 64 + mi * 16 + lm;
            af[mi] = *(short8*)&Pt[buf][r * 32 + swz(r, qd) * 8];
        }
        #pragma unroll
        for (int ni = 0; ni < 4; ni++) {
            int r = dh * 64 + ni * 16 + lm;
            bf8[ni] = *(short8*)&Gt[buf][r * 32 + swz(r, qd) * 8];
        }
        #pragma unroll
        for (int mi = 0; mi < 4; mi++)
            #pragma unroll
            for (int ni = 0; ni < 4; ni++)
                acc[mi][ni] = __builtin_amdgcn_mfma_f32_16x16x32_bf16(af[mi], bf8[ni], acc[mi][ni], 0, 0, 0);
        __syncthreads();
    }
#undef STAGE_D

    float* Dp = Dacc_part + (size_t)kc * BD;
    #pragma unroll
    for (int mi = 0; mi < 4; mi++)
        #pragma unroll
        for (int ni = 0; ni < 4; ni++) {
            int d = dbase + dh * 64 + ni * 16 + lm;
            #pragma unroll
            for (int i = 0; i < 4; i++) {
                int m = mh * 64 + mi * 16 + qd * 4 + i;
                Dp[(size_t)m * D_SZ + d] = acc[mi][ni][i];
            }
        }
}

// ---------------- epilogue: out = (sum_kc Dacc_part / L - x)/sig ----------
__global__ __launch_bounds__(256) void epilogue_kernel(
        const float* __restrict__ Dacc_part, const float* __restrict__ L,
        const float* __restrict__ x, const float* __restrict__ tarr,
        float* __restrict__ out)
{
    int i = (blockIdx.x * 256 + threadIdx.x) * 4;   // grid 384: covers BD
    int b = i / D_SZ;
    f32x4 s = (f32x4){0.f, 0.f, 0.f, 0.f};
    #pragma unroll
    for (int kc = 0; kc < KC_D; kc++)
        s += *(const f32x4*)(Dacc_part + (size_t)kc * BD + i);
    float tt = tarr[b] / 999.0f;
    float sig = 1.0f - tt;
    float invL = 1.0f / L[b];
    f32x4 xv = *(const f32x4*)(x + i);
    f32x4 o;
    #pragma unroll
    for (int j = 0; j < 4; j++) o[j] = (s[j] * invL - xv[j]) / sig;
    *(f32x4*)(out + i) = o;
}

extern "C" void kernel_launch(void* const* d_in, const int* in_sizes, int n_in,
                              void* d_out, int out_size, void* d_ws, size_t ws_size,
                              hipStream_t stream)
{
    const float* xt = (const float*)d_in[0];   // [128,3,32,32]
    const float* t  = (const float*)d_in[1];   // [128]
    const float* gt = (const float*)d_in[2];   // [20000,3,32,32]
    float* out = (float*)d_out;

    char* ws = (char*)d_ws;
    float*          XG_part  = (float*)(ws + 0);             // 4*BN*4   = 41943040
    float*          XG       = (float*)(ws + 41943040);      // BN*4     = 10485760
    float*          Dacc_part= (float*)(ws + 52428800);      // 40*BD*4  = 62914560
    float*          G2       = (float*)(ws + 115343360);     // 81920  } zeroed
    unsigned*       Mkey     = (unsigned*)(ws + 115425280);  //   512  } contiguous
    float*          L        = (float*)(ws + 115425792);     //   512  } 20736 f32
    unsigned short* X_t      = (unsigned short*)(ws + 115426304); // 1572864
    unsigned short* P_t      = (unsigned short*)(ws + 116999168); // 5242880
    unsigned short* GS       = (unsigned short*)(ws + 122242048); // 246153216
    unsigned short* GD       = (unsigned short*)(ws + 368395264); // 125829120
    // end ~494 MB (< ws poison size 983 MB)

    zero_small    <<<   81, 256, 0, stream>>>(G2);           // G2+Mkey+L
    prep_x        <<< 1536, 256, 0, stream>>>(xt, X_t);
    prep_gt       <<< 1920, 256, 0, stream>>>(gt, GS, GD, G2);
    scores_kernel <<< 1252, 256, 0, stream>>>(GS, X_t, XG_part);
    sum4max       <<< 2560, 256, 0, stream>>>(XG_part, G2, t, XG, Mkey);
    expk          <<< 1024, 256, 0, stream>>>(XG, G2, t, Mkey, P_t, L);
    drift_kernel  <<<  960, 256, 0, stream>>>(GD, P_t, Dacc_part);
    epilogue_kernel<<< 384, 256, 0, stream>>>(Dacc_part, L, xt, t, out);
}